// Round 3
// baseline (564.716 us; speedup 1.0000x reference)
//
#include <hip/hip_runtime.h>
#include <stdint.h>

// Problem constants (match the reference).
#define B 256
#define K 64
#define L 32
#define SENTINEL 32u
#define NUM_SLOTS 100000
#define HALF 64

// R7: single wide-grid fused kernel. 8 blocks per batch (2048 blocks x 256
// threads). Each block redundantly builds the full per-batch LDS hash (4096
// slots; insert duplication x8 is ~5 us of aggregate LDS-atomic time, hidden
// under stores from co-resident blocks), then resolves + stores only its
// 512-row output slice. vs R6: removes the thin 256-block resolve kernel
// (suspected ~100 us of latency-bound, 1-block/CU hash work), the 2 MB codes
// round-trip, and one launch. Store phase keeps full concurrency:
// 49.7 KB LDS -> 3 blocks (12 waves)/CU, 2048 blocks deep.
//
// Per-block phases:
//   0: init hash + stage lens (128 u32) in LDS
//   1: insert ALL 4096 batch elements (scatter-min, shared-key table)
//   1.5: resolve this block's 512 rows -> u16 codes in LDS (probe once/row)
//   2: stream 512 rows x 512 B to out (8 lanes/row, 4x float4 per lane-task,
//      128 B-contiguous segments per 8-lane group -> full lines, no RFO)

#define HASH_SIZE 4096
#define HASH_MASK 4095u
#define THREADS 256
#define SLICES 8                       // blocks per batch
#define EPB (2 * K * L)                // elements per batch = 4096
#define SLICE_ROWS (EPB / SLICES)      // 512 rows per block

typedef float fvec4 __attribute__((ext_vector_type(4)));

__global__ __launch_bounds__(THREADS) void wpe_fused_wide_kernel(
    const int* __restrict__ src_walks,
    const int* __restrict__ tgt_walks,
    const int* __restrict__ src_lens,
    const int* __restrict__ tgt_lens,
    const float* __restrict__ own_emb,
    const float* __restrict__ cross_emb,
    fvec4* __restrict__ out) {
  __shared__ int            s_keys[HASH_SIZE];
  __shared__ unsigned int   s_vsrc[HASH_SIZE];
  __shared__ unsigned int   s_vtgt[HASH_SIZE];
  __shared__ int            s_lens[2 * K];
  __shared__ unsigned short s_code[SLICE_ROWS];

  const unsigned int b    = blockIdx.x >> 3;   // batch
  const unsigned int s    = blockIdx.x & 7u;   // slice within batch
  const unsigned int t    = threadIdx.x;
  const unsigned int base = b * (K * L);       // flat (b,0,0) into walks

  // ---- Phase 0: init hash + stage lens ----
  for (unsigned int i = t; i < HASH_SIZE; i += THREADS) {
    s_keys[i] = 0;
    s_vsrc[i] = SENTINEL;
    s_vtgt[i] = SENTINEL;
  }
  if (t < 2 * K) {
    s_lens[t] = (t < K) ? src_lens[b * K + t] : tgt_lens[b * K + (t - K)];
  }
  __syncthreads();

  // ---- Phase 1: scatter-min ALL batch elements into the LDS hash ----
  for (unsigned int e = t; e < EPB; e += THREADS) {
    unsigned int which = e >> 11;
    unsigned int idx   = e & 2047u;
    unsigned int l     = idx & (L - 1);
    unsigned int k     = idx >> 5;
    const int* walks = which ? tgt_walks : src_walks;
    int node = walks[base + idx];
    int len  = s_lens[which * K + k];
    if ((int)l < len && node != 0) {
      unsigned int h = ((unsigned int)node * 0x9E3779B1u) >> 20;  // top 12 bits
      while (true) {
        int prev = atomicCAS(&s_keys[h], 0, node);
        if (prev == 0 || prev == node) break;
        h = (h + 1) & HASH_MASK;
      }
      if (which) atomicMin(&s_vtgt[h], l);
      else       atomicMin(&s_vsrc[h], l);
    }
  }
  __syncthreads();

  // ---- Phase 1.5: resolve this slice's 512 rows -> packed u16 codes ----
  // code = pown | pcross<<6 ; 0xFFFF = invalid (emit zeros).
  for (unsigned int j = t; j < SLICE_ROWS; j += THREADS) {
    unsigned int e     = s * SLICE_ROWS + j;
    unsigned int which = e >> 11;
    unsigned int idx   = e & 2047u;
    unsigned int l     = idx & (L - 1);
    unsigned int k     = idx >> 5;
    const int* walks = which ? tgt_walks : src_walks;
    int node = walks[base + idx];        // L2-hot (phase 1 read it)
    int len  = s_lens[which * K + k];
    unsigned short code = 0xFFFFu;
    if ((int)l < len && node != 0) {
      unsigned int h = ((unsigned int)node * 0x9E3779B1u) >> 20;
      while (s_keys[h] != node) h = (h + 1) & HASH_MASK;  // guaranteed present
      unsigned int ps = s_vsrc[h];
      unsigned int pt = s_vtgt[h];
      unsigned int pown   = which ? pt : ps;
      unsigned int pcross = which ? ps : pt;
      code = (unsigned short)(pown | (pcross << 6));
    }
    s_code[j] = code;
  }
  __syncthreads();

  // ---- Phase 2: stream this slice's rows to out ----
  // lane-task id: j = id>>3 (row within slice), c = id&7 (float4 quarter-col).
  for (unsigned int it = 0; it < SLICE_ROWS * 8u / THREADS; ++it) {
    unsigned int id = it * THREADS + t;
    unsigned int j  = id >> 3;
    unsigned int c  = id & 7u;
    unsigned int e     = s * SLICE_ROWS + j;
    unsigned int which = e >> 11;
    unsigned int idx   = e & 2047u;
    unsigned int code  = s_code[j];

    fvec4 vo0, vo1, vc0, vc1;
    if (code != 0xFFFFu) {
      unsigned int pown   = code & 63u;
      unsigned int pcross = (code >> 6) & 63u;
      const fvec4* eo = (const fvec4*)(own_emb   + pown   * HALF);
      const fvec4* ec = (const fvec4*)(cross_emb + pcross * HALF);
      vo0 = eo[c];
      vo1 = eo[c + 8u];
      vc0 = ec[c];
      vc1 = ec[c + 8u];
    } else {
      vo0 = vo1 = vc0 = vc1 = (fvec4)(0.f, 0.f, 0.f, 0.f);
    }
    unsigned int row = which * (unsigned int)(B * K * L) + base + idx;
    unsigned int ob  = row * 32u;
    out[ob + c]       = vo0;
    out[ob + 8u + c]  = vo1;
    out[ob + 16u + c] = vc0;
    out[ob + 24u + c] = vc1;
  }
}

// ---------------------------------------------------------------------------
extern "C" void kernel_launch(void* const* d_in, const int* in_sizes, int n_in,
                              void* d_out, int out_size, void* d_ws, size_t ws_size,
                              hipStream_t stream) {
  const int*   src_walks = (const int*)d_in[0];
  const int*   tgt_walks = (const int*)d_in[1];
  const int*   src_lens  = (const int*)d_in[2];
  const int*   tgt_lens  = (const int*)d_in[3];
  const float* own_emb   = (const float*)d_in[4];
  const float* cross_emb = (const float*)d_in[5];

  // Single fused launch: 8 slices per batch, hash duplicated per block.
  wpe_fused_wide_kernel<<<B * SLICES, THREADS, 0, stream>>>(
      src_walks, tgt_walks, src_lens, tgt_lens, own_emb, cross_emb,
      (fvec4*)d_out);
}

// Round 4
// 537.057 us; speedup vs baseline: 1.0515x; 1.0515x over previous
//
#include <hip/hip_runtime.h>
#include <stdint.h>

// Problem constants (match the reference).
#define B 256
#define K 64
#define L 32
#define SENTINEL 32u
#define NUM_SLOTS 100000
#define HALF 64

// R8: back to the R6 two-kernel split (R7's x8-duplicated hash build was a
// ~25 us regression), with two changes:
//
//  1) Expand kernel store pattern: R6/R7 wrote 8 scattered 128 B segments per
//     store instruction (8 lanes/row). Measured ~2.8-3.3 TB/s vs the 6.2 TB/s
//     the harness fill achieves -> suspected L2-transaction fan-out cap, not
//     HBM. Now a wave's 64 lanes write 64 CONSECUTIVE float4s (1 KB fully
//     contiguous per store instruction, the fill's pattern). Lanes 0-31 =
//     row r cols 0-31, lanes 32-63 = row r+1. own/cross half is an address
//     select (no divergence); gathers are 4x 256 B L1-resident segments.
//
//  2) Resolve kernel: record each element's hash slot during insert
//     (s_slot[e], 8 KB LDS) so phase 2 is direct LDS reads -- no walk
//     reload, no re-probe.

#define HASH_SIZE 4096
#define HASH_MASK 4095u
#define RESOLVE_THREADS 1024
#define EPB (2 * K * L)                 // elements (rows) per batch = 4096
#define ROWS (2 * B * K * L)            // 1,048,576 output rows
#define ROWPITCH 32u                    // fvec4 per row (128 floats)

typedef float fvec4 __attribute__((ext_vector_type(4)));

// ---------------------------------------------------------------------------
// Kernel 1: per-batch LDS hash build + per-element resolve -> u16 codes.
// code = pown | pcross<<6 ; 0xFFFF = invalid row (emit zeros downstream).
// ---------------------------------------------------------------------------
__global__ __launch_bounds__(RESOLVE_THREADS) void wpe_resolve_kernel(
    const int* __restrict__ src_walks,
    const int* __restrict__ tgt_walks,
    const int* __restrict__ src_lens,
    const int* __restrict__ tgt_lens,
    unsigned short* __restrict__ codes) {
  __shared__ int            s_keys[HASH_SIZE];
  __shared__ unsigned int   s_vsrc[HASH_SIZE];
  __shared__ unsigned int   s_vtgt[HASH_SIZE];
  __shared__ unsigned short s_slot[EPB];
  __shared__ int            s_lens[2 * K];

  const unsigned int b = blockIdx.x;
  const unsigned int t = threadIdx.x;
  const unsigned int base = b * (K * L);

  // ---- Phase 0: init hash + stage lens ----
  for (unsigned int i = t; i < HASH_SIZE; i += RESOLVE_THREADS) {
    s_keys[i] = 0;
    s_vsrc[i] = SENTINEL;
    s_vtgt[i] = SENTINEL;
  }
  if (t < 2 * K) {
    s_lens[t] = (t < K) ? src_lens[b * K + t] : tgt_lens[b * K + (t - K)];
  }
  __syncthreads();

  // ---- Phase 1: scatter-min into hash, recording each element's slot ----
  for (unsigned int e = t; e < EPB; e += RESOLVE_THREADS) {
    unsigned int which = e >> 11;
    unsigned int idx   = e & 2047u;
    unsigned int l     = idx & (L - 1);
    unsigned int k     = idx >> 5;
    const int* walks = which ? tgt_walks : src_walks;
    int node = walks[base + idx];
    int len  = s_lens[which * K + k];
    unsigned short slot = 0xFFFFu;
    if ((int)l < len && node != 0) {
      unsigned int h = ((unsigned int)node * 0x9E3779B1u) >> 20;  // top 12 bits
      while (true) {
        int prev = atomicCAS(&s_keys[h], 0, node);
        if (prev == 0 || prev == node) break;
        h = (h + 1) & HASH_MASK;
      }
      if (which) atomicMin(&s_vtgt[h], l);
      else       atomicMin(&s_vsrc[h], l);
      slot = (unsigned short)h;
    }
    s_slot[e] = slot;
  }
  __syncthreads();

  // ---- Phase 2: direct slot lookup -> packed u16 code ----
  for (unsigned int e = t; e < EPB; e += RESOLVE_THREADS) {
    unsigned int which = e >> 11;
    unsigned int slot  = s_slot[e];
    unsigned short code = 0xFFFFu;
    if (slot != 0xFFFFu) {
      unsigned int ps = s_vsrc[slot];
      unsigned int pt = s_vtgt[slot];
      unsigned int pown   = which ? pt : ps;
      unsigned int pcross = which ? ps : pt;
      code = (unsigned short)(pown | (pcross << 6));
    }
    codes[b * (unsigned)(K * L) + which * (unsigned)(B * K * L) + (e & 2047u)] = code;
  }
}

// ---------------------------------------------------------------------------
// Kernel 2: expand codes -> embeddings, wave-contiguous stores.
// Block of 256 threads covers 1024 consecutive fvec4 entries = 32 rows.
// Iteration it: entry = blockBase + it*256 + t  -> each wave stores 1 KB
// fully contiguous. Lane's (row, col): row = entry>>5, col = entry&31;
// col<16 -> own half, col>=16 -> cross half (address select, no branch).
// ---------------------------------------------------------------------------
__global__ __launch_bounds__(256) void wpe_expand_kernel(
    const unsigned short* __restrict__ codes,
    const float* __restrict__ own_emb,
    const float* __restrict__ cross_emb,
    fvec4* __restrict__ out) {
  __shared__ unsigned short s_code[32];

  const unsigned int t = threadIdx.x;
  const unsigned int rowBase = blockIdx.x * 32u;          // 32 rows per block
  const unsigned int entryBase = blockIdx.x * 1024u;

  if (t < 32u) s_code[t] = codes[rowBase + t];
  __syncthreads();

  const fvec4* own4   = (const fvec4*)own_emb;    // [33][16]
  const fvec4* cross4 = (const fvec4*)cross_emb;  // [33][16]

#pragma unroll
  for (unsigned int it = 0; it < 4; ++it) {
    unsigned int lid = it * 256u + t;        // 0..1023 within block
    unsigned int lr  = lid >> 5;             // local row 0..31
    unsigned int col = lid & 31u;            // fvec4 column within row

    unsigned int code = s_code[lr];
    fvec4 v = (fvec4)(0.f, 0.f, 0.f, 0.f);
    if (code != 0xFFFFu) {
      unsigned int pown   = code & 63u;
      unsigned int pcross = (code >> 6) & 63u;
      const fvec4* p = (col < 16u) ? (own4   + pown   * 16u + col)
                                   : (cross4 + pcross * 16u + (col - 16u));
      v = *p;
    }
    out[entryBase + lid] = v;
  }
}

// ---------------------------------------------------------------------------
extern "C" void kernel_launch(void* const* d_in, const int* in_sizes, int n_in,
                              void* d_out, int out_size, void* d_ws, size_t ws_size,
                              hipStream_t stream) {
  const int*   src_walks = (const int*)d_in[0];
  const int*   tgt_walks = (const int*)d_in[1];
  const int*   src_lens  = (const int*)d_in[2];
  const int*   tgt_lens  = (const int*)d_in[3];
  const float* own_emb   = (const float*)d_in[4];
  const float* cross_emb = (const float*)d_in[5];

  unsigned short* codes = (unsigned short*)d_ws;  // 2 MB

  // Step 1: per-batch hash build + element resolve (thin grid, LDS-heavy).
  wpe_resolve_kernel<<<B, RESOLVE_THREADS, 0, stream>>>(
      src_walks, tgt_walks, src_lens, tgt_lens, codes);

  // Step 2: streaming expand, wave-contiguous 1 KB stores.
  {
    const unsigned int blocks = ROWS / 32u;  // 32,768 blocks x 256 threads
    wpe_expand_kernel<<<blocks, 256, 0, stream>>>(
        codes, own_emb, cross_emb, (fvec4*)d_out);
  }
}